// Round 1
// baseline (518.410 us; speedup 1.0000x reference)
//
#include <hip/hip_runtime.h>

// Lorenz SDE, ShARK scheme, additive noise. Pure streaming kernel:
//   read x [B,3], dW [B,5,3], dH [B,5,3]  (fp32), write yT [B,3].
// 604 MB total traffic -> HBM-bound, roofline ~96 us at 6.3 TB/s.
//
// Layout is AoS (15 floats per point in dW/dH), so we stage each block's
// chunk through LDS with coalesced float4 loads, then each thread consumes
// its own point's data at stride 15 (gcd(15,32)=1 -> conflict-free banks).

#define NSTEPS 5
#define BLOCK 256

__global__ __launch_bounds__(BLOCK) void lorenz_shark(
    const float* __restrict__ x,
    const float* __restrict__ dW,
    const float* __restrict__ dH,
    float* __restrict__ out)
{
    __shared__ float s_x[BLOCK * 3];       // 3 KB
    __shared__ float s_w[BLOCK * 15];      // 15 KB
    __shared__ float s_h[BLOCK * 15];      // 15 KB

    const int tid = threadIdx.x;
    const long long ptBase = (long long)blockIdx.x * BLOCK;

    // ---- stage x: 768 floats = 192 float4, coalesced ----
    const float4* gx = (const float4*)(x + ptBase * 3);
    if (tid < 192) ((float4*)s_x)[tid] = gx[tid];

    // ---- stage dW/dH: 3840 floats = 960 float4 each, coalesced ----
    const float4* gw = (const float4*)(dW + ptBase * 15);
    const float4* gh = (const float4*)(dH + ptBase * 15);
#pragma unroll
    for (int k = 0; k < 3; ++k) {
        ((float4*)s_w)[tid + k * BLOCK] = gw[tid + k * BLOCK];
        ((float4*)s_h)[tid + k * BLOCK] = gh[tid + k * BLOCK];
    }
    {
        const int j = tid + 3 * BLOCK;   // 768..1023; need < 960
        if (j < 960) {
            ((float4*)s_w)[j] = gw[j];
            ((float4*)s_h)[j] = gh[j];
        }
    }
    __syncthreads();

    float a = s_x[3 * tid + 0];
    float b = s_x[3 * tid + 1];
    float c = s_x[3 * tid + 2];

    const float cW   = 0.2f;                  // NOISE * sqrt(dt)   = 2*0.1
    const float cH   = 0.05773502691896258f;  // NOISE * sqrt(dt/12)
    const float dt   = 0.01f;
    const float c56  = 5.0f / 6.0f;
    const float c56dt = c56 * dt;
    const float SIGMA = 10.0f;
    const float RHO   = 28.0f;
    const float BETA  = 8.0f / 3.0f;

#pragma unroll
    for (int n = 0; n < NSTEPS; ++n) {
        const int w0 = 15 * tid + 3 * n;
        const float wa = s_w[w0 + 0] * cW;
        const float wb = s_w[w0 + 1] * cW;
        const float wc = s_w[w0 + 2] * cW;
        const float ha = s_h[w0 + 0] * cH;
        const float hb = s_h[w0 + 1] * cH;
        const float hc = s_h[w0 + 2] * cH;

        // z1 = y + h
        const float z1a = a + ha, z1b = b + hb, z1c = c + hc;
        const float f1a = SIGMA * (z1b - z1a);
        const float f1b = z1a * (RHO - z1c) - z1b;
        const float f1c = z1a * z1b - BETA * z1c;

        // z2 = y + (5/6)dt f1 + (5/6)w + h
        const float z2a = a + c56dt * f1a + c56 * wa + ha;
        const float z2b = b + c56dt * f1b + c56 * wb + hb;
        const float z2c = c + c56dt * f1c + c56 * wc + hc;
        const float f2a = SIGMA * (z2b - z2a);
        const float f2b = z2a * (RHO - z2c) - z2b;
        const float f2c = z2a * z2b - BETA * z2c;

        // y1 = y + dt(0.4 f1 + 0.6 f2) + w
        a = a + dt * (0.4f * f1a + 0.6f * f2a) + wa;
        b = b + dt * (0.4f * f1b + 0.6f * f2b) + wb;
        c = c + dt * (0.4f * f1c + 0.6f * f2c) + wc;
    }

    // Each thread reads/writes only its own s_x[3t..3t+2]; no barrier needed
    // before the write, only before the coalesced float4 read-out.
    s_x[3 * tid + 0] = a;
    s_x[3 * tid + 1] = b;
    s_x[3 * tid + 2] = c;
    __syncthreads();

    float4* go = (float4*)(out + ptBase * 3);
    if (tid < 192) go[tid] = ((float4*)s_x)[tid];
}

extern "C" void kernel_launch(void* const* d_in, const int* in_sizes, int n_in,
                              void* d_out, int out_size, void* d_ws, size_t ws_size,
                              hipStream_t stream) {
    const float* x  = (const float*)d_in[0];
    const float* dW = (const float*)d_in[1];
    const float* dH = (const float*)d_in[2];
    float* out = (float*)d_out;

    const int batch = in_sizes[0] / 3;        // 4194304, divisible by BLOCK
    const int nblocks = batch / BLOCK;        // 16384

    hipLaunchKernelGGL(lorenz_shark, dim3(nblocks), dim3(BLOCK), 0, stream,
                       x, dW, dH, out);
}

// Round 2
// 518.303 us; speedup vs baseline: 1.0002x; 1.0002x over previous
//
#include <hip/hip_runtime.h>

// Lorenz SDE, ShARK scheme. Streaming: read x[B,3], dW[B,5,3], dH[B,5,3] fp32,
// write yT[B,3]. 604 MB logical traffic -> HBM-bound roofline ~96 us.
//
// R1 structure: wave-autonomous tiles. Each 64-lane wave stages its own
// 64-point chunk (3.84KB w + 3.84KB h + 768B x) into a PRIVATE LDS slice with
// coalesced float4 loads, computes, and writes back -- NO __syncthreads().
// Intra-wave LDS ordering is guaranteed by in-order DS execution per wave;
// __builtin_amdgcn_wave_barrier() prevents compiler reordering.
// This decouples the 16 waves/CU into independent pipelines instead of 4
// barrier-coupled blocks (R0 was latency-bound at 169us: VALUBusy 14%,
// BW 24%, occupancy 38% -- classic barrier-drain coupling).

#define NSTEPS 5
#define BLOCK 256
#define WPB 4          // waves per block
#define TILE 64        // points per wave

__global__ __launch_bounds__(BLOCK) void lorenz_shark(
    const float* __restrict__ x,
    const float* __restrict__ dW,
    const float* __restrict__ dH,
    float* __restrict__ out)
{
    __shared__ float s_w[WPB][TILE * 15];   // 15 KB
    __shared__ float s_h[WPB][TILE * 15];   // 15 KB
    __shared__ float s_x[WPB][TILE * 3];    // 3 KB   (33 KB total, 4 blk/CU)

    const int lane = threadIdx.x & 63;
    const int wv   = threadIdx.x >> 6;
    const long long ptBase = ((long long)blockIdx.x * WPB + wv) * TILE;

    const float4* gw = (const float4*)(dW + ptBase * 15);   // 240 float4
    const float4* gh = (const float4*)(dH + ptBase * 15);   // 240 float4
    const float4* gx = (const float4*)(x  + ptBase * 3);    //  48 float4

    float4* lw = (float4*)s_w[wv];
    float4* lh = (float4*)s_h[wv];
    float4* lx = (float4*)s_x[wv];

    // ---- stage: perfectly coalesced, ~8 outstanding float4 loads/lane ----
#pragma unroll
    for (int k = 0; k < 3; ++k) {
        lw[lane + k * 64] = gw[lane + k * 64];
        lh[lane + k * 64] = gh[lane + k * 64];
    }
    if (lane < 48) {
        lw[lane + 192] = gw[lane + 192];
        lh[lane + 192] = gh[lane + 192];
        lx[lane]       = gx[lane];
    }
    __builtin_amdgcn_wave_barrier();   // pin compiler order: writes before reads

    float a = s_x[wv][3 * lane + 0];
    float b = s_x[wv][3 * lane + 1];
    float c = s_x[wv][3 * lane + 2];

    const float cW    = 0.2f;                  // NOISE * sqrt(dt)
    const float cH    = 0.05773502691896258f;  // NOISE * sqrt(dt/12)
    const float dt    = 0.01f;
    const float c56   = 5.0f / 6.0f;
    const float c56dt = c56 * dt;
    const float SIGMA = 10.0f;
    const float RHO   = 28.0f;
    const float BETA  = 8.0f / 3.0f;

#pragma unroll
    for (int n = 0; n < NSTEPS; ++n) {
        const int w0 = 15 * lane + 3 * n;      // stride 15: 2 lanes/bank, free
        const float wa = s_w[wv][w0 + 0] * cW;
        const float wb = s_w[wv][w0 + 1] * cW;
        const float wc = s_w[wv][w0 + 2] * cW;
        const float ha = s_h[wv][w0 + 0] * cH;
        const float hb = s_h[wv][w0 + 1] * cH;
        const float hc = s_h[wv][w0 + 2] * cH;

        // z1 = y + h
        const float z1a = a + ha, z1b = b + hb, z1c = c + hc;
        const float f1a = SIGMA * (z1b - z1a);
        const float f1b = z1a * (RHO - z1c) - z1b;
        const float f1c = z1a * z1b - BETA * z1c;

        // z2 = y + (5/6)dt f1 + (5/6)w + h
        const float z2a = a + c56dt * f1a + c56 * wa + ha;
        const float z2b = b + c56dt * f1b + c56 * wb + hb;
        const float z2c = c + c56dt * f1c + c56 * wc + hc;
        const float f2a = SIGMA * (z2b - z2a);
        const float f2b = z2a * (RHO - z2c) - z2b;
        const float f2c = z2a * z2b - BETA * z2c;

        // y1 = y + dt(0.4 f1 + 0.6 f2) + w
        a = a + dt * (0.4f * f1a + 0.6f * f2a) + wa;
        b = b + dt * (0.4f * f1b + 0.6f * f2b) + wb;
        c = c + dt * (0.4f * f1c + 0.6f * f2c) + wc;
    }

    // result -> LDS slice -> coalesced float4 store (intra-wave, no barrier)
    s_x[wv][3 * lane + 0] = a;
    s_x[wv][3 * lane + 1] = b;
    s_x[wv][3 * lane + 2] = c;
    __builtin_amdgcn_wave_barrier();

    float4* go = (float4*)(out + ptBase * 3);
    if (lane < 48) go[lane] = lx[lane];
}

extern "C" void kernel_launch(void* const* d_in, const int* in_sizes, int n_in,
                              void* d_out, int out_size, void* d_ws, size_t ws_size,
                              hipStream_t stream) {
    const float* x  = (const float*)d_in[0];
    const float* dW = (const float*)d_in[1];
    const float* dH = (const float*)d_in[2];
    float* out = (float*)d_out;

    const int batch   = in_sizes[0] / 3;          // 4194304
    const int nblocks = batch / (WPB * TILE);     // 16384

    hipLaunchKernelGGL(lorenz_shark, dim3(nblocks), dim3(BLOCK), 0, stream,
                       x, dW, dH, out);
}